// Round 9
// baseline (210.986 us; speedup 1.0000x reference)
//
#include <hip/hip_runtime.h>

// ---------------- types / helpers ----------------
using bf16x8 = __attribute__((ext_vector_type(8))) short;
using f32x4  = __attribute__((ext_vector_type(4))) float;

static __device__ inline unsigned short f2bf(float f) {
  unsigned int u = __float_as_uint(f);
  u += 0x7fffu + ((u >> 16) & 1u);          // round-to-nearest-even
  return (unsigned short)(u >> 16);
}
static __device__ inline unsigned int pk2(float a, float b) {
  return (unsigned int)f2bf(a) | ((unsigned int)f2bf(b) << 16);
}

// Barrier draining LDS ops only; global loads (vmcnt) stay in flight.
#define BAR_LGKM() { asm volatile("s_waitcnt lgkmcnt(0)" ::: "memory"); \
                     __builtin_amdgcn_sched_barrier(0); \
                     __builtin_amdgcn_s_barrier(); }

// butterfly reductions across the 16-lane DPP row (row_ror 1,2,4,8)
#define ROW16_MAX(x) { \
  { int _t = __builtin_amdgcn_update_dpp(0, __float_as_int(x), 0x121, 0xf, 0xf, true); x = fmaxf(x, __int_as_float(_t)); } \
  { int _t = __builtin_amdgcn_update_dpp(0, __float_as_int(x), 0x122, 0xf, 0xf, true); x = fmaxf(x, __int_as_float(_t)); } \
  { int _t = __builtin_amdgcn_update_dpp(0, __float_as_int(x), 0x124, 0xf, 0xf, true); x = fmaxf(x, __int_as_float(_t)); } \
  { int _t = __builtin_amdgcn_update_dpp(0, __float_as_int(x), 0x128, 0xf, 0xf, true); x = fmaxf(x, __int_as_float(_t)); } }
#define ROW16_SUM(x) { \
  { int _t = __builtin_amdgcn_update_dpp(0, __float_as_int(x), 0x121, 0xf, 0xf, true); x += __int_as_float(_t); } \
  { int _t = __builtin_amdgcn_update_dpp(0, __float_as_int(x), 0x122, 0xf, 0xf, true); x += __int_as_float(_t); } \
  { int _t = __builtin_amdgcn_update_dpp(0, __float_as_int(x), 0x124, 0xf, 0xf, true); x += __int_as_float(_t); } \
  { int _t = __builtin_amdgcn_update_dpp(0, __float_as_int(x), 0x128, 0xf, 0xf, true); x += __int_as_float(_t); } }

// ---------------- kernel 0: weight prep (transpose -> bf16) ----------------
__global__ __launch_bounds__(256) void prep_kernel(
    const float* __restrict__ Wq, const float* __restrict__ Wk, const float* __restrict__ Wv,
    const float* __restrict__ Wo, const float* __restrict__ bq, const float* __restrict__ bk,
    const float* __restrict__ bv,
    unsigned short* __restrict__ Wt, unsigned short* __restrict__ Wot, float* __restrict__ bqkv)
{
  int idx = blockIdx.x * 256 + threadIdx.x;
  if (idx < 192 * 1024) {
    int n = idx >> 10, k = idx & 1023;
    const float* W = (n < 64) ? Wq : (n < 128) ? Wk : Wv;
    Wt[idx] = f2bf(W[k * 64 + (n & 63)]);
  } else if (idx < 192 * 1024 + 1024 * 64) {
    int j = idx - 192 * 1024;
    int n = j >> 6, k = j & 63;
    Wot[j] = f2bf(Wo[k * 1024 + n]);
  } else if (idx < 192 * 1024 + 1024 * 64 + 192) {
    int n = idx - (192 * 1024 + 1024 * 64);
    bqkv[n] = (n < 64) ? bq[n] : (n < 128) ? bk[n - 64] : bv[n - 128];
  }
}

// ---------------- fused kernel: QKV proj + banded attention + out proj ----------------
// Block = 64 q-rows, grid 256 (1 block/CU), 1024 threads = 16 waves (4/SIMD).
// Phase 1: window GEMM [192 rows] x [192 qkv] x K=1024, BK=64 dbuf,
//          DISTANCE-2 register prefetch (counted-vmcnt barriers keep loads
//          in flight across barriers; covers ~900cy HBM first-touch misses).
// Phase 2: banded attention; 4 q-subtiles (g) x 4 worker waves (u) each.
// Phase 3: output projection; Wot fragments prefetched right after phase 1.
// LDS map (bytes):
//   phase 1: A dbuf [0, 55296), B dbuf [55296, 110592)   (192 x 72 shorts each)
//   phase 2: Kl [0, 27648), Vt [27648, 55296),
//            PsU [55296, 76800)  time-muxed: Q(64x72) -> P(4x16x168) -> Obf(64x72)
//   always : Mx [110592), Lx [111616), biasL [112640)   (outside phase-1 region)

#define P1_LOAD(KS, PA, PB) { \
  _Pragma("unroll") \
  for (int i_ = 0; i_ < 3; ++i_) { \
    PA[i_] = *(const float4*)(xbase + offA[i_] + (KS) * 64); \
    PB[i_] = *(const uint2*)(Wt + offB[i_] + (KS) * 64); } }

#define P1_STORE(AB, BB, PA, PB) { \
  _Pragma("unroll") \
  for (int i_ = 0; i_ < 3; ++i_) { \
    *(uint2*)((AB) + (i_ * 64 + tr) * 72 + c4 * 4) = \
        make_uint2(pk2(PA[i_].x, PA[i_].y), pk2(PA[i_].z, PA[i_].w)); \
    *(uint2*)((BB) + (i_ * 64 + tr) * 72 + c4 * 4) = PB[i_]; } }

#define P1_MMA(AB, BB) { \
  __builtin_amdgcn_s_setprio(1); \
  _Pragma("unroll") \
  for (int kk = 0; kk < 64; kk += 32) { \
    int ko = kk + quad * 8; \
    bf16x8 bfr[3]; \
    _Pragma("unroll") \
    for (int nt = 0; nt < 3; ++nt) \
      bfr[nt] = *(const bf16x8*)((BB) + ((wn * 3 + nt) * 16 + col) * 72 + ko); \
    _Pragma("unroll") \
    for (int mt = 0; mt < 3; ++mt) { \
      bf16x8 afr = *(const bf16x8*)((AB) + ((wm * 3 + mt) * 16 + col) * 72 + ko); \
      _Pragma("unroll") \
      for (int nt = 0; nt < 3; ++nt) \
        acc[mt][nt] = __builtin_amdgcn_mfma_f32_16x16x32_bf16(afr, bfr[nt], acc[mt][nt], 0, 0, 0); \
    } } \
  __builtin_amdgcn_s_setprio(0); }

__global__ __launch_bounds__(1024, 4) void fused_attn(
    const float* __restrict__ X, const unsigned short* __restrict__ Wt,
    const float* __restrict__ bqkv, const float* __restrict__ bias,
    const unsigned short* __restrict__ Wot, const float* __restrict__ bo,
    float* __restrict__ out)
{
  __shared__ __align__(16) char smem[113664];
  unsigned short* const Kl  = (unsigned short*)(smem);            // [192][72]
  unsigned short* const Vt  = (unsigned short*)(smem + 27648);    // [64][216]
  unsigned short* const PsU = (unsigned short*)(smem + 55296);    // Q / P / Obf
  float* const Mx    = (float*)(smem + 110592);                   // [16][16]
  float* const Lx    = (float*)(smem + 111616);                   // [16][16]
  float* const biasL = (float*)(smem + 112640);                   // [129]
  unsigned short* const As_ = (unsigned short*)(smem);            // [2][192*72]
  unsigned short* const Bs_ = (unsigned short*)(smem + 55296);    // [2][192*72]

  int t = threadIdx.x;
  int lane = t & 63, w = t >> 6;
  int col = lane & 15, quad = lane >> 4, q4 = quad * 4;
  // XCD swizzle: each XCD gets one batch's 32 contiguous q-tiles (halo L2 reuse).
  int L = ((blockIdx.x & 7) << 5) | (blockIdx.x >> 3);
  int b = L >> 5;                    // batch
  int i0 = (L & 31) * 64;            // first q row (batch coords)
  const float* xbase = X + (size_t)(b << 11) * 1024;

  if (t < 129) biasL[t] = bias[1984 + t];   // region untouched by phase 1

  // ---- phase 1: window GEMM, BK=64, dbuf, distance-2 reg prefetch ----
  int wm = w >> 2, wn = w & 3;       // wave tile: 48 rows x 48 cols
  f32x4 acc[3][3] = {};
  int tr = t >> 4, c4 = t & 15;      // staging: 64 rows/slab, 16 chunks of 4
  int offA[3], offB[3];
  #pragma unroll
  for (int i = 0; i < 3; ++i) {
    int row = i * 64 + tr;           // window row 0..191
    int jb = i0 - 64 + row;
    int jc = jb < 0 ? 0 : (jb > 2047 ? 2047 : jb);
    offA[i] = jc * 1024 + c4 * 4;
    offB[i] = row * 1024 + c4 * 4;
  }
  float bov[3];
  #pragma unroll
  for (int nt = 0; nt < 3; ++nt) bov[nt] = bqkv[wn * 48 + nt * 16 + col];

  float4 pA0[3], pA1[3]; uint2 pB0[3], pB1[3];
  P1_LOAD(0, pA0, pB0);
  P1_LOAD(1, pA1, pB1);
  unsigned short* const A0 = As_;            unsigned short* const B0 = Bs_;
  unsigned short* const A1 = As_ + 13824;    unsigned short* const B1 = Bs_ + 13824;
  for (int ks = 0; ks < 16; ks += 2) {
    P1_STORE(A0, B0, pA0, pB0);
    if (ks + 2 < 16) P1_LOAD(ks + 2, pA0, pB0);
    BAR_LGKM();
    P1_MMA(A0, B0);
    // race-free: prior-iter MMA(buf1) readers drained their own lgkmcnt
    // before signalling the barrier above; store(buf1) is after it.
    P1_STORE(A1, B1, pA1, pB1);
    if (ks + 3 < 16) P1_LOAD(ks + 3, pA1, pB1);
    BAR_LGKM();
    P1_MMA(A1, B1);
  }
  BAR_LGKM();        // last-buf ds_reads done before LDS repurpose

  // ---- prefetch phase-3 operands; lgkm-only barriers keep them in flight ----
  int n0 = w * 64;
  const unsigned short* wb_base = Wot + (size_t)(n0 + col) * 64 + quad * 8;
  bf16x8 wb[4][2];
  #pragma unroll
  for (int ns = 0; ns < 4; ++ns) {
    wb[ns][0] = *(const bf16x8*)(wb_base + ns * 16 * 64);
    wb[ns][1] = *(const bf16x8*)(wb_base + ns * 16 * 64 + 32);
  }
  float bov4[4];
  #pragma unroll
  for (int ns = 0; ns < 4; ++ns) bov4[ns] = bo[n0 + ns * 16 + col];

  // ---- phase 1b: accumulators (+bias, ->bf16) into phase-2 layouts ----
  #pragma unroll
  for (int mt = 0; mt < 3; ++mt) {
    #pragma unroll
    for (int nt = 0; nt < 3; ++nt) {
      int n = wn * 48 + nt * 16 + col;
      int mbase = wm * 48 + mt * 16 + q4;
      if (n < 64) {                            // Q (middle 64 window rows)
        #pragma unroll
        for (int r = 0; r < 4; ++r) {
          int m = mbase + r;
          if (m >= 64 && m < 128) PsU[(m - 64) * 72 + n] = f2bf(acc[mt][nt][r] + bov[nt]);
        }
      } else if (n < 128) {                    // K: per-element (stride-72 scatter)
        #pragma unroll
        for (int r = 0; r < 4; ++r)
          Kl[(mbase + r) * 72 + (n - 64)] = f2bf(acc[mt][nt][r] + bov[nt]);
      } else {                                 // V^T: m contiguous -> one uint2
        uint2 pv = make_uint2(
            pk2(acc[mt][nt][0] + bov[nt], acc[mt][nt][1] + bov[nt]),
            pk2(acc[mt][nt][2] + bov[nt], acc[mt][nt][3] + bov[nt]));
        *(uint2*)(Vt + (n - 128) * 216 + mbase) = pv;
      }
    }
  }
  if (t < 256) { // zero-fill Vt j-cols 192..207 (PV k-chunk overhang)
    int pz = t >> 2, c0 = 192 + (t & 3) * 4;
    *(uint2*)(Vt + pz * 216 + c0) = make_uint2(0u, 0u);
  }
  BAR_LGKM();

  // ---- phase 2: banded attention; g = q-subtile (16 rows), u = worker ----
  int g = w >> 2, u = w & 3;
  int iq = i0 + g * 16;
  bf16x8 aq0 = *(const bf16x8*)(PsU + (g * 16 + col) * 72 + quad * 8);
  bf16x8 aq1 = *(const bf16x8*)(PsU + (g * 16 + col) * 72 + 32 + quad * 8);

  // QK^T: j-tiles split u=0:{0,1,2} u=1:{3,4} u=2:{5,6} u=3:{7,8}
  int nt9 = (u == 0) ? 3 : 2;
  int t9b = (u == 0) ? 0 : (2 * u + 1);
  f32x4 sv[3];
  for (int i = 0; i < nt9; ++i) {
    int t9 = t9b + i;
    int krow = ((g + t9) * 16 + col) * 72;
    bf16x8 kb0 = *(const bf16x8*)(Kl + krow + quad * 8);
    bf16x8 kb1 = *(const bf16x8*)(Kl + krow + 32 + quad * 8);
    f32x4 z = {};
    z = __builtin_amdgcn_mfma_f32_16x16x32_bf16(aq0, kb0, z, 0, 0, 0);
    sv[i] = __builtin_amdgcn_mfma_f32_16x16x32_bf16(aq1, kb1, z, 0, 0, 0);
  }
  float mrow[4] = {-3e38f, -3e38f, -3e38f, -3e38f};
  for (int i = 0; i < nt9; ++i) {
    int t9 = t9b + i;
    int j = iq - 64 + t9 * 16 + col;
    #pragma unroll
    for (int r = 0; r < 4; ++r) {
      int diff = q4 + r + 64 - t9 * 16 - col;   // i - j
      bool valid = (j >= 0) & (j < 2048) & (diff >= -64) & (diff <= 64);
      int bi = 64 - diff; bi = bi < 0 ? 0 : (bi > 128 ? 128 : bi);
      float x = valid ? (sv[i][r] * 0.125f + biasL[bi]) : -3e38f;
      sv[i][r] = x;
      mrow[r] = fmaxf(mrow[r], x);
    }
  }
  #pragma unroll
  for (int r = 0; r < 4; ++r) ROW16_MAX(mrow[r]);
  if (col == 0) {
    #pragma unroll
    for (int r = 0; r < 4; ++r) Mx[w * 16 + q4 + r] = mrow[r];
  }
  BAR_LGKM();
  #pragma unroll
  for (int r = 0; r < 4; ++r) {
    float m0_ = Mx[(g * 4 + 0) * 16 + q4 + r];
    float m1_ = Mx[(g * 4 + 1) * 16 + q4 + r];
    float m2_ = Mx[(g * 4 + 2) * 16 + q4 + r];
    float m3_ = Mx[(g * 4 + 3) * 16 + q4 + r];
    mrow[r] = fmaxf(fmaxf(m0_, m1_), fmaxf(m2_, m3_));
  }

  unsigned short* Pw = PsU + g * 2688;       // 16 rows x 168
  float lsum[4] = {0.f, 0.f, 0.f, 0.f};
  for (int i = 0; i < nt9; ++i) {
    int t9 = t9b + i;
    #pragma unroll
    for (int r = 0; r < 4; ++r) {
      float pe = __expf(sv[i][r] - mrow[r]);
      lsum[r] += pe;
      Pw[(q4 + r) * 168 + t9 * 16 + col] = f2bf(pe);
    }
  }
  #pragma unroll
  for (int r = 0; r < 4; ++r) ROW16_SUM(lsum[r]);
  if (col == 0) {
    #pragma unroll
    for (int r = 0; r < 4; ++r) Lx[w * 16 + q4 + r] = lsum[r];
  }
  if (u == 0) {
    #pragma unroll
    for (int r = 0; r < 4; ++r) Pw[(q4 + r) * 168 + 144 + col] = 0;
  }
  BAR_LGKM();
  #pragma unroll
  for (int r = 0; r < 4; ++r)
    lsum[r] = Lx[(g * 4 + 0) * 16 + q4 + r] + Lx[(g * 4 + 1) * 16 + q4 + r]
            + Lx[(g * 4 + 2) * 16 + q4 + r] + Lx[(g * 4 + 3) * 16 + q4 + r];

  // PV: wave u owns p-block u (16 cols) over all 5 k-chunks
  f32x4 o = {};
  #pragma unroll
  for (int kc = 0; kc < 5; ++kc) {
    bf16x8 pa = *(const bf16x8*)(Pw + col * 168 + kc * 32 + quad * 8);
    bf16x8 vb = *(const bf16x8*)(Vt + (u * 16 + col) * 216 + g * 16 + kc * 32 + quad * 8);
    o = __builtin_amdgcn_mfma_f32_16x16x32_bf16(pa, vb, o, 0, 0, 0);
  }
  BAR_LGKM();   // all P reads drained before Obf overwrites PsU
  {
    float rl[4];
    #pragma unroll
    for (int r = 0; r < 4; ++r) rl[r] = 1.0f / lsum[r];
    #pragma unroll
    for (int r = 0; r < 4; ++r)
      PsU[(g * 16 + q4 + r) * 72 + u * 16 + col] = f2bf(o[r] * rl[r]);
  }
  BAR_LGKM();

  // ---- phase 3: out[64 q][1024 n] = Obf @ Wot + bo; wave owns 64 n-cols ----
  float* outbase = out + ((size_t)(b << 11) + i0) * 1024 + n0;
  #pragma unroll
  for (int mt = 0; mt < 4; ++mt) {
    bf16x8 a0 = *(const bf16x8*)(PsU + (mt * 16 + col) * 72 + quad * 8);
    bf16x8 a1 = *(const bf16x8*)(PsU + (mt * 16 + col) * 72 + 32 + quad * 8);
    f32x4 a4[4] = {};
    #pragma unroll
    for (int ns = 0; ns < 4; ++ns) {
      a4[ns] = __builtin_amdgcn_mfma_f32_16x16x32_bf16(a0, wb[ns][0], a4[ns], 0, 0, 0);
      a4[ns] = __builtin_amdgcn_mfma_f32_16x16x32_bf16(a1, wb[ns][1], a4[ns], 0, 0, 0);
    }
    #pragma unroll
    for (int ns = 0; ns < 4; ++ns)
      #pragma unroll
      for (int r = 0; r < 4; ++r)
        outbase[(size_t)(mt * 16 + q4 + r) * 1024 + ns * 16 + col] = a4[ns][r] + bov4[ns];
  }
}

// ---------------- launch ----------------
extern "C" void kernel_launch(void* const* d_in, const int* in_sizes, int n_in,
                              void* d_out, int out_size, void* d_ws, size_t ws_size,
                              hipStream_t stream) {
  const float* X    = (const float*)d_in[0];
  // d_in[1] = attention_mask: per-row constant shift -> softmax-invariant, unused
  const float* Wq   = (const float*)d_in[2];
  const float* bq   = (const float*)d_in[3];
  const float* Wk   = (const float*)d_in[4];
  const float* bk   = (const float*)d_in[5];
  const float* Wv   = (const float*)d_in[6];
  const float* bv   = (const float*)d_in[7];
  const float* Wo   = (const float*)d_in[8];
  const float* bo   = (const float*)d_in[9];
  const float* bias = (const float*)d_in[10];
  float* out = (float*)d_out;
  char* ws = (char*)d_ws;
  unsigned short* Wt   = (unsigned short*)(ws);              //   393,216 B
  unsigned short* Wot  = (unsigned short*)(ws + 393216);     //   131,072 B
  float*          bqkv = (float*)(ws + 524288);              //       768 B

  prep_kernel<<<1025, 256, 0, stream>>>(Wq, Wk, Wv, Wo, bq, bk, bv, Wt, Wot, bqkv);
  fused_attn<<<256, 1024, 0, stream>>>(X, Wt, bqkv, bias, Wot, bo, out);
}

// Round 10
// 157.802 us; speedup vs baseline: 1.3370x; 1.3370x over previous
//
#include <hip/hip_runtime.h>

// ---------------- types / helpers ----------------
using bf16x8 = __attribute__((ext_vector_type(8))) short;
using f32x4  = __attribute__((ext_vector_type(4))) float;

static __device__ inline unsigned short f2bf(float f) {
  unsigned int u = __float_as_uint(f);
  u += 0x7fffu + ((u >> 16) & 1u);          // round-to-nearest-even
  return (unsigned short)(u >> 16);
}
static __device__ inline unsigned int pk2(float a, float b) {
  return (unsigned int)f2bf(a) | ((unsigned int)f2bf(b) << 16);
}

// Barrier draining LDS ops only; global loads (vmcnt) stay in flight.
#define BAR_LGKM() { asm volatile("s_waitcnt lgkmcnt(0)" ::: "memory"); \
                     __builtin_amdgcn_sched_barrier(0); \
                     __builtin_amdgcn_s_barrier(); }

// butterfly reductions across the 16-lane DPP row (row_ror 1,2,4,8)
#define ROW16_MAX(x) { \
  { int _t = __builtin_amdgcn_update_dpp(0, __float_as_int(x), 0x121, 0xf, 0xf, true); x = fmaxf(x, __int_as_float(_t)); } \
  { int _t = __builtin_amdgcn_update_dpp(0, __float_as_int(x), 0x122, 0xf, 0xf, true); x = fmaxf(x, __int_as_float(_t)); } \
  { int _t = __builtin_amdgcn_update_dpp(0, __float_as_int(x), 0x124, 0xf, 0xf, true); x = fmaxf(x, __int_as_float(_t)); } \
  { int _t = __builtin_amdgcn_update_dpp(0, __float_as_int(x), 0x128, 0xf, 0xf, true); x = fmaxf(x, __int_as_float(_t)); } }
#define ROW16_SUM(x) { \
  { int _t = __builtin_amdgcn_update_dpp(0, __float_as_int(x), 0x121, 0xf, 0xf, true); x += __int_as_float(_t); } \
  { int _t = __builtin_amdgcn_update_dpp(0, __float_as_int(x), 0x122, 0xf, 0xf, true); x += __int_as_float(_t); } \
  { int _t = __builtin_amdgcn_update_dpp(0, __float_as_int(x), 0x124, 0xf, 0xf, true); x += __int_as_float(_t); } \
  { int _t = __builtin_amdgcn_update_dpp(0, __float_as_int(x), 0x128, 0xf, 0xf, true); x += __int_as_float(_t); } }

// ---------------- kernel 0: weight prep (transpose -> bf16) ----------------
__global__ __launch_bounds__(256) void prep_kernel(
    const float* __restrict__ Wq, const float* __restrict__ Wk, const float* __restrict__ Wv,
    const float* __restrict__ Wo, const float* __restrict__ bq, const float* __restrict__ bk,
    const float* __restrict__ bv,
    unsigned short* __restrict__ Wt, unsigned short* __restrict__ Wot, float* __restrict__ bqkv)
{
  int idx = blockIdx.x * 256 + threadIdx.x;
  if (idx < 192 * 1024) {
    int n = idx >> 10, k = idx & 1023;
    const float* W = (n < 64) ? Wq : (n < 128) ? Wk : Wv;
    Wt[idx] = f2bf(W[k * 64 + (n & 63)]);
  } else if (idx < 192 * 1024 + 1024 * 64) {
    int j = idx - 192 * 1024;
    int n = j >> 6, k = j & 63;
    Wot[j] = f2bf(Wo[k * 1024 + n]);
  } else if (idx < 192 * 1024 + 1024 * 64 + 192) {
    int n = idx - (192 * 1024 + 1024 * 64);
    bqkv[n] = (n < 64) ? bq[n] : (n < 128) ? bk[n - 64] : bv[n - 128];
  }
}

// ---------------- fused kernel: QKV proj + banded attention + out proj ----------------
// Block = 64 q-rows, grid 256 (1 block/CU), 1024 threads = 16 waves (4/SIMD).
// R8 structure (55 us verified). R10 adds only register-neutral deltas:
// packed uint2 V^T stores in phase 1b, setprio around phase-1 MFMA.
// NOTE (R9 lesson): compiler pins this kernel at the 64-VGPR occupancy step
// and SPILLS if pressure exceeds it — no distance-2 prefetch, no wb hoist.
// LDS map (bytes):
//   phase 1: A dbuf [0, 55296), B dbuf [55296, 110592)   (192 x 72 shorts each)
//   phase 2: Kl [0, 27648), Vt [27648, 55296),
//            PsU [55296, 76800)  time-muxed: Q(64x72) -> P(4x16x168) -> Obf(64x72)
//   always : Mx [110592), Lx [111616), biasL [112640)   (outside phase-1 region)
__global__ __launch_bounds__(1024, 4) void fused_attn(
    const float* __restrict__ X, const unsigned short* __restrict__ Wt,
    const float* __restrict__ bqkv, const float* __restrict__ bias,
    const unsigned short* __restrict__ Wot, const float* __restrict__ bo,
    float* __restrict__ out)
{
  __shared__ __align__(16) char smem[113664];
  unsigned short* const Kl  = (unsigned short*)(smem);            // [192][72]
  unsigned short* const Vt  = (unsigned short*)(smem + 27648);    // [64][216]
  unsigned short* const PsU = (unsigned short*)(smem + 55296);    // Q / P / Obf
  float* const Mx    = (float*)(smem + 110592);                   // [16][16]
  float* const Lx    = (float*)(smem + 111616);                   // [16][16]
  float* const biasL = (float*)(smem + 112640);                   // [129]
  unsigned short* const As_ = (unsigned short*)(smem);            // [2][192*72]
  unsigned short* const Bs_ = (unsigned short*)(smem + 55296);    // [2][192*72]

  int t = threadIdx.x;
  int lane = t & 63, w = t >> 6;
  int col = lane & 15, quad = lane >> 4, q4 = quad * 4;
  // XCD swizzle: each XCD gets one batch's 32 contiguous q-tiles (halo L2 reuse).
  int L = ((blockIdx.x & 7) << 5) | (blockIdx.x >> 3);
  int b = L >> 5;                    // batch
  int i0 = (L & 31) * 64;            // first q row (batch coords)
  const float* xbase = X + (size_t)(b << 11) * 1024;

  if (t < 129) biasL[t] = bias[1984 + t];   // region untouched by phase 1

  // ---- phase 1: window GEMM, BK=64, double-buffered, distance-1 prefetch ----
  int wm = w >> 2, wn = w & 3;       // wave tile: 48 rows x 48 cols
  f32x4 acc[3][3] = {};
  int tr = t >> 4, c4 = t & 15;      // staging: 64 rows/slab, 16 chunks of 4
  int offA[3], offB[3];
  #pragma unroll
  for (int i = 0; i < 3; ++i) {
    int row = i * 64 + tr;           // window row 0..191
    int jb = i0 - 64 + row;
    int jc = jb < 0 ? 0 : (jb > 2047 ? 2047 : jb);
    offA[i] = jc * 1024 + c4 * 4;
    offB[i] = row * 1024 + c4 * 4;
  }
  float bov[3];
  #pragma unroll
  for (int nt = 0; nt < 3; ++nt) bov[nt] = bqkv[wn * 48 + nt * 16 + col];

  float4 pA[3]; uint2 pB[3];
  #pragma unroll
  for (int i = 0; i < 3; ++i) {
    pA[i] = *(const float4*)(xbase + offA[i]);
    pB[i] = *(const uint2*)(Wt + offB[i]);
  }
  for (int ks = 0; ks < 16; ++ks) {
    unsigned short* A  = As_ + (ks & 1) * 13824;
    unsigned short* Bb = Bs_ + (ks & 1) * 13824;
    #pragma unroll
    for (int i = 0; i < 3; ++i) {    // staged regs -> LDS[cur]
      *(uint2*)(A  + (i * 64 + tr) * 72 + c4 * 4) =
          make_uint2(pk2(pA[i].x, pA[i].y), pk2(pA[i].z, pA[i].w));
      *(uint2*)(Bb + (i * 64 + tr) * 72 + c4 * 4) = pB[i];
    }
    if (ks + 1 < 16) {               // next tile's loads issued before barrier
      #pragma unroll
      for (int i = 0; i < 3; ++i) {
        pA[i] = *(const float4*)(xbase + offA[i] + (ks + 1) * 64);
        pB[i] = *(const uint2*)(Wt + offB[i] + (ks + 1) * 64);
      }
    }
    BAR_LGKM();
    // race-free: a wave's buf-X ds_reads drain (own lgkmcnt 0) before it
    // signals the next barrier; buf-X is rewritten 2 iters later, after it.
    __builtin_amdgcn_s_setprio(1);
    #pragma unroll
    for (int kk = 0; kk < 64; kk += 32) {
      int ko = kk + quad * 8;
      bf16x8 bfr[3];
      #pragma unroll
      for (int nt = 0; nt < 3; ++nt)
        bfr[nt] = *(const bf16x8*)(Bb + ((wn * 3 + nt) * 16 + col) * 72 + ko);
      #pragma unroll
      for (int mt = 0; mt < 3; ++mt) {
        bf16x8 afr = *(const bf16x8*)(A + ((wm * 3 + mt) * 16 + col) * 72 + ko);
        #pragma unroll
        for (int nt = 0; nt < 3; ++nt)
          acc[mt][nt] = __builtin_amdgcn_mfma_f32_16x16x32_bf16(afr, bfr[nt], acc[mt][nt], 0, 0, 0);
      }
    }
    __builtin_amdgcn_s_setprio(0);
  }
  BAR_LGKM();        // last-buf ds_reads done before LDS repurpose

  // ---- phase 1b: accumulators (+bias, ->bf16) into phase-2 layouts ----
  #pragma unroll
  for (int mt = 0; mt < 3; ++mt) {
    #pragma unroll
    for (int nt = 0; nt < 3; ++nt) {
      int n = wn * 48 + nt * 16 + col;
      int mbase = wm * 48 + mt * 16 + q4;
      if (n < 64) {                            // Q (middle 64 window rows)
        #pragma unroll
        for (int r = 0; r < 4; ++r) {
          int m = mbase + r;
          if (m >= 64 && m < 128) PsU[(m - 64) * 72 + n] = f2bf(acc[mt][nt][r] + bov[nt]);
        }
      } else if (n < 128) {                    // K: stride-72 scatter (j varies per reg)
        #pragma unroll
        for (int r = 0; r < 4; ++r)
          Kl[(mbase + r) * 72 + (n - 64)] = f2bf(acc[mt][nt][r] + bov[nt]);
      } else {                                 // V^T: m contiguous -> one uint2
        uint2 pv = make_uint2(
            pk2(acc[mt][nt][0] + bov[nt], acc[mt][nt][1] + bov[nt]),
            pk2(acc[mt][nt][2] + bov[nt], acc[mt][nt][3] + bov[nt]));
        *(uint2*)(Vt + (n - 128) * 216 + mbase) = pv;
      }
    }
  }
  if (t < 256) { // zero-fill Vt j-cols 192..207 (PV k-chunk overhang)
    int pz = t >> 2, c0 = 192 + (t & 3) * 4;
    *(uint2*)(Vt + pz * 216 + c0) = make_uint2(0u, 0u);
  }
  BAR_LGKM();

  // ---- phase 2: banded attention; g = q-subtile (16 rows), u = worker ----
  int g = w >> 2, u = w & 3;
  int iq = i0 + g * 16;
  bf16x8 aq0 = *(const bf16x8*)(PsU + (g * 16 + col) * 72 + quad * 8);
  bf16x8 aq1 = *(const bf16x8*)(PsU + (g * 16 + col) * 72 + 32 + quad * 8);

  // QK^T: j-tiles split u=0:{0,1,2} u=1:{3,4} u=2:{5,6} u=3:{7,8}
  int nt9 = (u == 0) ? 3 : 2;
  int t9b = (u == 0) ? 0 : (2 * u + 1);
  f32x4 sv[3];
  for (int i = 0; i < nt9; ++i) {
    int t9 = t9b + i;
    int krow = ((g + t9) * 16 + col) * 72;
    bf16x8 kb0 = *(const bf16x8*)(Kl + krow + quad * 8);
    bf16x8 kb1 = *(const bf16x8*)(Kl + krow + 32 + quad * 8);
    f32x4 z = {};
    z = __builtin_amdgcn_mfma_f32_16x16x32_bf16(aq0, kb0, z, 0, 0, 0);
    sv[i] = __builtin_amdgcn_mfma_f32_16x16x32_bf16(aq1, kb1, z, 0, 0, 0);
  }
  float mrow[4] = {-3e38f, -3e38f, -3e38f, -3e38f};
  for (int i = 0; i < nt9; ++i) {
    int t9 = t9b + i;
    int j = iq - 64 + t9 * 16 + col;
    #pragma unroll
    for (int r = 0; r < 4; ++r) {
      int diff = q4 + r + 64 - t9 * 16 - col;   // i - j
      bool valid = (j >= 0) & (j < 2048) & (diff >= -64) & (diff <= 64);
      int bi = 64 - diff; bi = bi < 0 ? 0 : (bi > 128 ? 128 : bi);
      float x = valid ? (sv[i][r] * 0.125f + biasL[bi]) : -3e38f;
      sv[i][r] = x;
      mrow[r] = fmaxf(mrow[r], x);
    }
  }
  #pragma unroll
  for (int r = 0; r < 4; ++r) ROW16_MAX(mrow[r]);
  if (col == 0) {
    #pragma unroll
    for (int r = 0; r < 4; ++r) Mx[w * 16 + q4 + r] = mrow[r];
  }
  BAR_LGKM();
  #pragma unroll
  for (int r = 0; r < 4; ++r) {
    float m0_ = Mx[(g * 4 + 0) * 16 + q4 + r];
    float m1_ = Mx[(g * 4 + 1) * 16 + q4 + r];
    float m2_ = Mx[(g * 4 + 2) * 16 + q4 + r];
    float m3_ = Mx[(g * 4 + 3) * 16 + q4 + r];
    mrow[r] = fmaxf(fmaxf(m0_, m1_), fmaxf(m2_, m3_));
  }

  unsigned short* Pw = PsU + g * 2688;       // 16 rows x 168
  float lsum[4] = {0.f, 0.f, 0.f, 0.f};
  for (int i = 0; i < nt9; ++i) {
    int t9 = t9b + i;
    #pragma unroll
    for (int r = 0; r < 4; ++r) {
      float pe = __expf(sv[i][r] - mrow[r]);
      lsum[r] += pe;
      Pw[(q4 + r) * 168 + t9 * 16 + col] = f2bf(pe);
    }
  }
  #pragma unroll
  for (int r = 0; r < 4; ++r) ROW16_SUM(lsum[r]);
  if (col == 0) {
    #pragma unroll
    for (int r = 0; r < 4; ++r) Lx[w * 16 + q4 + r] = lsum[r];
  }
  if (u == 0) {
    #pragma unroll
    for (int r = 0; r < 4; ++r) Pw[(q4 + r) * 168 + 144 + col] = 0;
  }
  BAR_LGKM();
  #pragma unroll
  for (int r = 0; r < 4; ++r)
    lsum[r] = Lx[(g * 4 + 0) * 16 + q4 + r] + Lx[(g * 4 + 1) * 16 + q4 + r]
            + Lx[(g * 4 + 2) * 16 + q4 + r] + Lx[(g * 4 + 3) * 16 + q4 + r];

  // PV: wave u owns p-block u (16 cols) over all 5 k-chunks
  f32x4 o = {};
  #pragma unroll
  for (int kc = 0; kc < 5; ++kc) {
    bf16x8 pa = *(const bf16x8*)(Pw + col * 168 + kc * 32 + quad * 8);
    bf16x8 vb = *(const bf16x8*)(Vt + (u * 16 + col) * 216 + g * 16 + kc * 32 + quad * 8);
    o = __builtin_amdgcn_mfma_f32_16x16x32_bf16(pa, vb, o, 0, 0, 0);
  }
  BAR_LGKM();   // all P reads drained before Obf overwrites PsU
  {
    float rl[4];
    #pragma unroll
    for (int r = 0; r < 4; ++r) rl[r] = 1.0f / lsum[r];
    #pragma unroll
    for (int r = 0; r < 4; ++r)
      PsU[(g * 16 + q4 + r) * 72 + u * 16 + col] = f2bf(o[r] * rl[r]);
  }
  BAR_LGKM();

  // ---- phase 3: out[64 q][1024 n] = Obf @ Wot + bo; wave owns 64 n-cols ----
  int n0 = w * 64;
  const unsigned short* wb_base = Wot + (size_t)(n0 + col) * 64 + quad * 8;
  bf16x8 wb[4][2];
  #pragma unroll
  for (int ns = 0; ns < 4; ++ns) {
    wb[ns][0] = *(const bf16x8*)(wb_base + ns * 16 * 64);
    wb[ns][1] = *(const bf16x8*)(wb_base + ns * 16 * 64 + 32);
  }
  float bov4[4];
  #pragma unroll
  for (int ns = 0; ns < 4; ++ns) bov4[ns] = bo[n0 + ns * 16 + col];
  float* outbase = out + ((size_t)(b << 11) + i0) * 1024 + n0;
  #pragma unroll
  for (int mt = 0; mt < 4; ++mt) {
    bf16x8 a0 = *(const bf16x8*)(PsU + (mt * 16 + col) * 72 + quad * 8);
    bf16x8 a1 = *(const bf16x8*)(PsU + (mt * 16 + col) * 72 + 32 + quad * 8);
    f32x4 a4[4] = {};
    #pragma unroll
    for (int ns = 0; ns < 4; ++ns) {
      a4[ns] = __builtin_amdgcn_mfma_f32_16x16x32_bf16(a0, wb[ns][0], a4[ns], 0, 0, 0);
      a4[ns] = __builtin_amdgcn_mfma_f32_16x16x32_bf16(a1, wb[ns][1], a4[ns], 0, 0, 0);
    }
    #pragma unroll
    for (int ns = 0; ns < 4; ++ns)
      #pragma unroll
      for (int r = 0; r < 4; ++r)
        outbase[(size_t)(mt * 16 + q4 + r) * 1024 + ns * 16 + col] = a4[ns][r] + bov4[ns];
  }
}

// ---------------- launch ----------------
extern "C" void kernel_launch(void* const* d_in, const int* in_sizes, int n_in,
                              void* d_out, int out_size, void* d_ws, size_t ws_size,
                              hipStream_t stream) {
  const float* X    = (const float*)d_in[0];
  // d_in[1] = attention_mask: per-row constant shift -> softmax-invariant, unused
  const float* Wq   = (const float*)d_in[2];
  const float* bq   = (const float*)d_in[3];
  const float* Wk   = (const float*)d_in[4];
  const float* bk   = (const float*)d_in[5];
  const float* Wv   = (const float*)d_in[6];
  const float* bv   = (const float*)d_in[7];
  const float* Wo   = (const float*)d_in[8];
  const float* bo   = (const float*)d_in[9];
  const float* bias = (const float*)d_in[10];
  float* out = (float*)d_out;
  char* ws = (char*)d_ws;
  unsigned short* Wt   = (unsigned short*)(ws);              //   393,216 B
  unsigned short* Wot  = (unsigned short*)(ws + 393216);     //   131,072 B
  float*          bqkv = (float*)(ws + 524288);              //       768 B

  prep_kernel<<<1025, 256, 0, stream>>>(Wq, Wk, Wv, Wo, bq, bk, bv, Wt, Wot, bqkv);
  fused_attn<<<256, 1024, 0, stream>>>(X, Wt, bqkv, bias, Wot, bo, out);
}

// Round 11
// 154.554 us; speedup vs baseline: 1.3651x; 1.0210x over previous
//
#include <hip/hip_runtime.h>

// ---------------- types / helpers ----------------
using bf16x8 = __attribute__((ext_vector_type(8))) short;
using f32x4  = __attribute__((ext_vector_type(4))) float;

static __device__ inline unsigned short f2bf(float f) {
  unsigned int u = __float_as_uint(f);
  u += 0x7fffu + ((u >> 16) & 1u);          // round-to-nearest-even
  return (unsigned short)(u >> 16);
}
static __device__ inline unsigned int pk2(float a, float b) {
  return (unsigned int)f2bf(a) | ((unsigned int)f2bf(b) << 16);
}

// Barrier draining LDS ops only; global loads (vmcnt) stay in flight.
#define BAR_LGKM() { asm volatile("s_waitcnt lgkmcnt(0)" ::: "memory"); \
                     __builtin_amdgcn_sched_barrier(0); \
                     __builtin_amdgcn_s_barrier(); }

// butterfly reductions across the 16-lane DPP row (row_ror 1,2,4,8)
#define ROW16_MAX(x) { \
  { int _t = __builtin_amdgcn_update_dpp(0, __float_as_int(x), 0x121, 0xf, 0xf, true); x = fmaxf(x, __int_as_float(_t)); } \
  { int _t = __builtin_amdgcn_update_dpp(0, __float_as_int(x), 0x122, 0xf, 0xf, true); x = fmaxf(x, __int_as_float(_t)); } \
  { int _t = __builtin_amdgcn_update_dpp(0, __float_as_int(x), 0x124, 0xf, 0xf, true); x = fmaxf(x, __int_as_float(_t)); } \
  { int _t = __builtin_amdgcn_update_dpp(0, __float_as_int(x), 0x128, 0xf, 0xf, true); x = fmaxf(x, __int_as_float(_t)); } }
#define ROW16_SUM(x) { \
  { int _t = __builtin_amdgcn_update_dpp(0, __float_as_int(x), 0x121, 0xf, 0xf, true); x += __int_as_float(_t); } \
  { int _t = __builtin_amdgcn_update_dpp(0, __float_as_int(x), 0x122, 0xf, 0xf, true); x += __int_as_float(_t); } \
  { int _t = __builtin_amdgcn_update_dpp(0, __float_as_int(x), 0x124, 0xf, 0xf, true); x += __int_as_float(_t); } \
  { int _t = __builtin_amdgcn_update_dpp(0, __float_as_int(x), 0x128, 0xf, 0xf, true); x += __int_as_float(_t); } }

// ---------------- kernel 0: weight prep (transpose -> bf16) ----------------
__global__ __launch_bounds__(256) void prep_kernel(
    const float* __restrict__ Wq, const float* __restrict__ Wk, const float* __restrict__ Wv,
    const float* __restrict__ Wo, const float* __restrict__ bq, const float* __restrict__ bk,
    const float* __restrict__ bv,
    unsigned short* __restrict__ Wt, unsigned short* __restrict__ Wot, float* __restrict__ bqkv)
{
  int idx = blockIdx.x * 256 + threadIdx.x;
  if (idx < 192 * 1024) {
    int n = idx >> 10, k = idx & 1023;
    const float* W = (n < 64) ? Wq : (n < 128) ? Wk : Wv;
    Wt[idx] = f2bf(W[k * 64 + (n & 63)]);
  } else if (idx < 192 * 1024 + 1024 * 64) {
    int j = idx - 192 * 1024;
    int n = j >> 6, k = j & 63;
    Wot[j] = f2bf(Wo[k * 1024 + n]);
  } else if (idx < 192 * 1024 + 1024 * 64 + 192) {
    int n = idx - (192 * 1024 + 1024 * 64);
    bqkv[n] = (n < 64) ? bq[n] : (n < 128) ? bk[n - 64] : bv[n - 128];
  }
}

// ---------------- fused kernel: QKV proj + banded attention + out proj ----------------
// Block = 64 q-rows, grid 256 (1 block/CU), 1024 threads = 16 waves (4/SIMD).
// R10 structure (54 us verified) with two deltas:
//  (a) phase-1 split: KV-GEMM 192x128 (16 waves of 48x32) + Q-GEMM 64x64
//      (16 waves of 16x16) — removes the 22% of MACs R10 computed-and-discarded
//      (Q for the 128 halo rows). 14 MFMA/wave/K-step vs 18; acc 28 regs vs 36.
//  (b) normalized O tile parked in the (dead after QK^T) Kl region — drops the
//      "P reads drained" barrier before the Obf write.
// NOTE (R9 lesson): compiler pins this kernel at the 64-VGPR occupancy step
// and SPILLS if pressure exceeds it — no distance-2 prefetch, no wb hoist.
// LDS map (bytes):
//   phase 1: A dbuf [0, 55296), B dbuf [55296, 110592)   (192 x 72 shorts each)
//   phase 2: Kl [0, 27648) (QK^T; then reused for Obf), Vt [27648, 55296),
//            PsU [55296, 76800)  time-muxed: Q(64x72) -> P(4x16x168)
//   always : Mx [110592), Lx [111616), biasL [112640)   (outside phase-1 region)
__global__ __launch_bounds__(1024, 4) void fused_attn(
    const float* __restrict__ X, const unsigned short* __restrict__ Wt,
    const float* __restrict__ bqkv, const float* __restrict__ bias,
    const unsigned short* __restrict__ Wot, const float* __restrict__ bo,
    float* __restrict__ out)
{
  __shared__ __align__(16) char smem[113664];
  unsigned short* const Kl  = (unsigned short*)(smem);            // [192][72]; later Obf [64][72]
  unsigned short* const Vt  = (unsigned short*)(smem + 27648);    // [64][216]
  unsigned short* const PsU = (unsigned short*)(smem + 55296);    // Q then P
  float* const Mx    = (float*)(smem + 110592);                   // [16][16]
  float* const Lx    = (float*)(smem + 111616);                   // [16][16]
  float* const biasL = (float*)(smem + 112640);                   // [129]
  unsigned short* const As_ = (unsigned short*)(smem);            // [2][192*72]
  unsigned short* const Bs_ = (unsigned short*)(smem + 55296);    // [2][192*72]

  int t = threadIdx.x;
  int lane = t & 63, w = t >> 6;
  int col = lane & 15, quad = lane >> 4, q4 = quad * 4;
  // XCD swizzle: each XCD gets one batch's 32 contiguous q-tiles (halo L2 reuse).
  int L = ((blockIdx.x & 7) << 5) | (blockIdx.x >> 3);
  int b = L >> 5;                    // batch
  int i0 = (L & 31) * 64;            // first q row (batch coords)
  const float* xbase = X + (size_t)(b << 11) * 1024;

  if (t < 129) biasL[t] = bias[1984 + t];   // region untouched by phase 1

  // ---- phase 1: window GEMM, BK=64, double-buffered, distance-1 prefetch ----
  // KV: wave (wm=w>>2, wn=w&3) owns 48 rows x 32 of the 128 K|V cols.
  // Q : wave (wm4=w&3, wn4=w>>2) owns 16 middle rows x 16 of the 64 Q cols.
  int wm = w >> 2, wn = w & 3;
  int wm4 = w & 3, wn4 = w >> 2;
  f32x4 acc[3][2] = {};
  f32x4 accq = {};
  int tr = t >> 4, c4 = t & 15;      // staging: 64 rows/slab, 16 chunks of 4
  int offA[3], offB[3];
  #pragma unroll
  for (int i = 0; i < 3; ++i) {
    int row = i * 64 + tr;           // window row 0..191
    int jb = i0 - 64 + row;
    int jc = jb < 0 ? 0 : (jb > 2047 ? 2047 : jb);
    offA[i] = jc * 1024 + c4 * 4;
    offB[i] = row * 1024 + c4 * 4;
  }
  float bov[2], bovq;
  #pragma unroll
  for (int nt = 0; nt < 2; ++nt) bov[nt] = bqkv[64 + wn * 32 + nt * 16 + col];
  bovq = bqkv[wn4 * 16 + col];

  float4 pA[3]; uint2 pB[3];
  #pragma unroll
  for (int i = 0; i < 3; ++i) {
    pA[i] = *(const float4*)(xbase + offA[i]);
    pB[i] = *(const uint2*)(Wt + offB[i]);
  }
  for (int ks = 0; ks < 16; ++ks) {
    unsigned short* A  = As_ + (ks & 1) * 13824;
    unsigned short* Bb = Bs_ + (ks & 1) * 13824;
    #pragma unroll
    for (int i = 0; i < 3; ++i) {    // staged regs -> LDS[cur]
      *(uint2*)(A  + (i * 64 + tr) * 72 + c4 * 4) =
          make_uint2(pk2(pA[i].x, pA[i].y), pk2(pA[i].z, pA[i].w));
      *(uint2*)(Bb + (i * 64 + tr) * 72 + c4 * 4) = pB[i];
    }
    if (ks + 1 < 16) {               // next tile's loads issued before barrier
      #pragma unroll
      for (int i = 0; i < 3; ++i) {
        pA[i] = *(const float4*)(xbase + offA[i] + (ks + 1) * 64);
        pB[i] = *(const uint2*)(Wt + offB[i] + (ks + 1) * 64);
      }
    }
    BAR_LGKM();
    // race-free: a wave's buf-X ds_reads drain (own lgkmcnt 0) before it
    // signals the next barrier; buf-X is rewritten 2 iters later, after it.
    __builtin_amdgcn_s_setprio(1);
    #pragma unroll
    for (int kk = 0; kk < 64; kk += 32) {
      int ko = kk + quad * 8;
      // KV-GEMM: B rows 64 + wn*32 + nt*16 (K and V weight cols)
      bf16x8 bfr[2];
      #pragma unroll
      for (int nt = 0; nt < 2; ++nt)
        bfr[nt] = *(const bf16x8*)(Bb + ((64 + wn * 32 + nt * 16) + col) * 72 + ko);
      #pragma unroll
      for (int mt = 0; mt < 3; ++mt) {
        bf16x8 afr = *(const bf16x8*)(A + ((wm * 48 + mt * 16) + col) * 72 + ko);
        #pragma unroll
        for (int nt = 0; nt < 2; ++nt)
          acc[mt][nt] = __builtin_amdgcn_mfma_f32_16x16x32_bf16(afr, bfr[nt], acc[mt][nt], 0, 0, 0);
      }
      // Q-GEMM: middle 64 A rows only, B rows 0..63 (Q weight cols)
      {
        bf16x8 aq_ = *(const bf16x8*)(A + ((64 + wm4 * 16) + col) * 72 + ko);
        bf16x8 bq_ = *(const bf16x8*)(Bb + ((wn4 * 16) + col) * 72 + ko);
        accq = __builtin_amdgcn_mfma_f32_16x16x32_bf16(aq_, bq_, accq, 0, 0, 0);
      }
    }
    __builtin_amdgcn_s_setprio(0);
  }
  BAR_LGKM();        // last-buf ds_reads done before LDS repurpose

  // ---- phase 1b: accumulators (+bias, ->bf16) into phase-2 layouts ----
  // Waves wn in {0,1} hold pure K cols; wn in {2,3} pure V cols. All waves hold Q.
  #pragma unroll
  for (int mt = 0; mt < 3; ++mt) {
    int mbase = wm * 48 + mt * 16 + q4;
    #pragma unroll
    for (int nt = 0; nt < 2; ++nt) {
      int n = wn * 32 + nt * 16 + col;         // 0..127 over K|V
      if (wn < 2) {                            // K: stride-72 scatter
        #pragma unroll
        for (int r = 0; r < 4; ++r)
          Kl[(mbase + r) * 72 + n] = f2bf(acc[mt][nt][r] + bov[nt]);
      } else {                                 // V^T: m contiguous -> one uint2
        uint2 pv = make_uint2(
            pk2(acc[mt][nt][0] + bov[nt], acc[mt][nt][1] + bov[nt]),
            pk2(acc[mt][nt][2] + bov[nt], acc[mt][nt][3] + bov[nt]));
        *(uint2*)(Vt + (n - 64) * 216 + mbase) = pv;
      }
    }
  }
  { // Q tile: rows 0..63 (window rows 64..127), cols 0..63
    #pragma unroll
    for (int r = 0; r < 4; ++r)
      PsU[(wm4 * 16 + q4 + r) * 72 + wn4 * 16 + col] = f2bf(accq[r] + bovq);
  }
  if (t < 256) { // zero-fill Vt j-cols 192..207 (PV k-chunk overhang)
    int pz = t >> 2, c0 = 192 + (t & 3) * 4;
    *(uint2*)(Vt + pz * 216 + c0) = make_uint2(0u, 0u);
  }
  BAR_LGKM();

  // ---- phase 2: banded attention; g = q-subtile (16 rows), u = worker ----
  int g = w >> 2, u = w & 3;
  int iq = i0 + g * 16;
  bf16x8 aq0 = *(const bf16x8*)(PsU + (g * 16 + col) * 72 + quad * 8);
  bf16x8 aq1 = *(const bf16x8*)(PsU + (g * 16 + col) * 72 + 32 + quad * 8);

  // QK^T: j-tiles split u=0:{0,1,2} u=1:{3,4} u=2:{5,6} u=3:{7,8}
  int nt9 = (u == 0) ? 3 : 2;
  int t9b = (u == 0) ? 0 : (2 * u + 1);
  f32x4 sv[3];
  for (int i = 0; i < nt9; ++i) {
    int t9 = t9b + i;
    int krow = ((g + t9) * 16 + col) * 72;
    bf16x8 kb0 = *(const bf16x8*)(Kl + krow + quad * 8);
    bf16x8 kb1 = *(const bf16x8*)(Kl + krow + 32 + quad * 8);
    f32x4 z = {};
    z = __builtin_amdgcn_mfma_f32_16x16x32_bf16(aq0, kb0, z, 0, 0, 0);
    sv[i] = __builtin_amdgcn_mfma_f32_16x16x32_bf16(aq1, kb1, z, 0, 0, 0);
  }
  float mrow[4] = {-3e38f, -3e38f, -3e38f, -3e38f};
  for (int i = 0; i < nt9; ++i) {
    int t9 = t9b + i;
    int j = iq - 64 + t9 * 16 + col;
    #pragma unroll
    for (int r = 0; r < 4; ++r) {
      int diff = q4 + r + 64 - t9 * 16 - col;   // i - j
      bool valid = (j >= 0) & (j < 2048) & (diff >= -64) & (diff <= 64);
      int bi = 64 - diff; bi = bi < 0 ? 0 : (bi > 128 ? 128 : bi);
      float x = valid ? (sv[i][r] * 0.125f + biasL[bi]) : -3e38f;
      sv[i][r] = x;
      mrow[r] = fmaxf(mrow[r], x);
    }
  }
  #pragma unroll
  for (int r = 0; r < 4; ++r) ROW16_MAX(mrow[r]);
  if (col == 0) {
    #pragma unroll
    for (int r = 0; r < 4; ++r) Mx[w * 16 + q4 + r] = mrow[r];
  }
  BAR_LGKM();   // also guarantees all Kl (QK^T) reads drained chip-wave-wide
  #pragma unroll
  for (int r = 0; r < 4; ++r) {
    float m0_ = Mx[(g * 4 + 0) * 16 + q4 + r];
    float m1_ = Mx[(g * 4 + 1) * 16 + q4 + r];
    float m2_ = Mx[(g * 4 + 2) * 16 + q4 + r];
    float m3_ = Mx[(g * 4 + 3) * 16 + q4 + r];
    mrow[r] = fmaxf(fmaxf(m0_, m1_), fmaxf(m2_, m3_));
  }

  unsigned short* Pw = PsU + g * 2688;       // 16 rows x 168
  float lsum[4] = {0.f, 0.f, 0.f, 0.f};
  for (int i = 0; i < nt9; ++i) {
    int t9 = t9b + i;
    #pragma unroll
    for (int r = 0; r < 4; ++r) {
      float pe = __expf(sv[i][r] - mrow[r]);
      lsum[r] += pe;
      Pw[(q4 + r) * 168 + t9 * 16 + col] = f2bf(pe);
    }
  }
  #pragma unroll
  for (int r = 0; r < 4; ++r) ROW16_SUM(lsum[r]);
  if (col == 0) {
    #pragma unroll
    for (int r = 0; r < 4; ++r) Lx[w * 16 + q4 + r] = lsum[r];
  }
  if (u == 0) {
    #pragma unroll
    for (int r = 0; r < 4; ++r) Pw[(q4 + r) * 168 + 144 + col] = 0;
  }
  BAR_LGKM();
  #pragma unroll
  for (int r = 0; r < 4; ++r)
    lsum[r] = Lx[(g * 4 + 0) * 16 + q4 + r] + Lx[(g * 4 + 1) * 16 + q4 + r]
            + Lx[(g * 4 + 2) * 16 + q4 + r] + Lx[(g * 4 + 3) * 16 + q4 + r];

  // PV: wave u owns p-block u (16 cols) over all 5 k-chunks
  f32x4 o = {};
  #pragma unroll
  for (int kc = 0; kc < 5; ++kc) {
    bf16x8 pa = *(const bf16x8*)(Pw + col * 168 + kc * 32 + quad * 8);
    bf16x8 vb = *(const bf16x8*)(Vt + (u * 16 + col) * 216 + g * 16 + kc * 32 + quad * 8);
    o = __builtin_amdgcn_mfma_f32_16x16x32_bf16(pa, vb, o, 0, 0, 0);
  }
  // Normalized O parked in the Kl region (dead since the Mx barrier) — no
  // barrier needed before these writes; P region stays untouched.
  {
    float rl[4];
    #pragma unroll
    for (int r = 0; r < 4; ++r) rl[r] = 1.0f / lsum[r];
    #pragma unroll
    for (int r = 0; r < 4; ++r)
      Kl[(g * 16 + q4 + r) * 72 + u * 16 + col] = f2bf(o[r] * rl[r]);
  }
  BAR_LGKM();

  // ---- phase 3: out[64 q][1024 n] = Obf @ Wot + bo; wave owns 64 n-cols ----
  int n0 = w * 64;
  const unsigned short* wb_base = Wot + (size_t)(n0 + col) * 64 + quad * 8;
  bf16x8 wb[4][2];
  #pragma unroll
  for (int ns = 0; ns < 4; ++ns) {
    wb[ns][0] = *(const bf16x8*)(wb_base + ns * 16 * 64);
    wb[ns][1] = *(const bf16x8*)(wb_base + ns * 16 * 64 + 32);
  }
  float bov4[4];
  #pragma unroll
  for (int ns = 0; ns < 4; ++ns) bov4[ns] = bo[n0 + ns * 16 + col];
  float* outbase = out + ((size_t)(b << 11) + i0) * 1024 + n0;
  #pragma unroll
  for (int mt = 0; mt < 4; ++mt) {
    bf16x8 a0 = *(const bf16x8*)(Kl + (mt * 16 + col) * 72 + quad * 8);
    bf16x8 a1 = *(const bf16x8*)(Kl + (mt * 16 + col) * 72 + 32 + quad * 8);
    f32x4 a4[4] = {};
    #pragma unroll
    for (int ns = 0; ns < 4; ++ns) {
      a4[ns] = __builtin_amdgcn_mfma_f32_16x16x32_bf16(a0, wb[ns][0], a4[ns], 0, 0, 0);
      a4[ns] = __builtin_amdgcn_mfma_f32_16x16x32_bf16(a1, wb[ns][1], a4[ns], 0, 0, 0);
    }
    #pragma unroll
    for (int ns = 0; ns < 4; ++ns)
      #pragma unroll
      for (int r = 0; r < 4; ++r)
        outbase[(size_t)(mt * 16 + q4 + r) * 1024 + ns * 16 + col] = a4[ns][r] + bov4[ns];
  }
}

// ---------------- launch ----------------
extern "C" void kernel_launch(void* const* d_in, const int* in_sizes, int n_in,
                              void* d_out, int out_size, void* d_ws, size_t ws_size,
                              hipStream_t stream) {
  const float* X    = (const float*)d_in[0];
  // d_in[1] = attention_mask: per-row constant shift -> softmax-invariant, unused
  const float* Wq   = (const float*)d_in[2];
  const float* bq   = (const float*)d_in[3];
  const float* Wk   = (const float*)d_in[4];
  const float* bk   = (const float*)d_in[5];
  const float* Wv   = (const float*)d_in[6];
  const float* bv   = (const float*)d_in[7];
  const float* Wo   = (const float*)d_in[8];
  const float* bo   = (const float*)d_in[9];
  const float* bias = (const float*)d_in[10];
  float* out = (float*)d_out;
  char* ws = (char*)d_ws;
  unsigned short* Wt   = (unsigned short*)(ws);              //   393,216 B
  unsigned short* Wot  = (unsigned short*)(ws + 393216);     //   131,072 B
  float*          bqkv = (float*)(ws + 524288);              //       768 B

  prep_kernel<<<1025, 256, 0, stream>>>(Wq, Wk, Wv, Wo, bq, bk, bv, Wt, Wot, bqkv);
  fused_attn<<<256, 1024, 0, stream>>>(X, Wt, bqkv, bias, Wot, bo, out);
}

// Round 12
// 153.440 us; speedup vs baseline: 1.3750x; 1.0073x over previous
//
#include <hip/hip_runtime.h>

// ---------------- types / helpers ----------------
using bf16x8 = __attribute__((ext_vector_type(8))) short;
using f32x4  = __attribute__((ext_vector_type(4))) float;

static __device__ inline unsigned short f2bf(float f) {   // cold paths only
  unsigned int u = __float_as_uint(f);
  u += 0x7fffu + ((u >> 16) & 1u);          // round-to-nearest-even
  return (unsigned short)(u >> 16);
}
// HW packed fp32->bf16 (RNE), 1 instruction for 2 values. No builtin on
// gfx950 — inline asm per learn_hip m240. Low word = lo, high word = hi.
static __device__ inline unsigned int cvtpk(float lo, float hi) {
  unsigned int r;
  asm("v_cvt_pk_bf16_f32 %0, %1, %2" : "=v"(r) : "v"(lo), "v"(hi));
  return r;
}

// Barrier draining LDS ops only; global loads (vmcnt) stay in flight.
#define BAR_LGKM() { asm volatile("s_waitcnt lgkmcnt(0)" ::: "memory"); \
                     __builtin_amdgcn_sched_barrier(0); \
                     __builtin_amdgcn_s_barrier(); }

// butterfly reductions across the 16-lane DPP row (row_ror 1,2,4,8)
#define ROW16_MAX(x) { \
  { int _t = __builtin_amdgcn_update_dpp(0, __float_as_int(x), 0x121, 0xf, 0xf, true); x = fmaxf(x, __int_as_float(_t)); } \
  { int _t = __builtin_amdgcn_update_dpp(0, __float_as_int(x), 0x122, 0xf, 0xf, true); x = fmaxf(x, __int_as_float(_t)); } \
  { int _t = __builtin_amdgcn_update_dpp(0, __float_as_int(x), 0x124, 0xf, 0xf, true); x = fmaxf(x, __int_as_float(_t)); } \
  { int _t = __builtin_amdgcn_update_dpp(0, __float_as_int(x), 0x128, 0xf, 0xf, true); x = fmaxf(x, __int_as_float(_t)); } }
#define ROW16_SUM(x) { \
  { int _t = __builtin_amdgcn_update_dpp(0, __float_as_int(x), 0x121, 0xf, 0xf, true); x += __int_as_float(_t); } \
  { int _t = __builtin_amdgcn_update_dpp(0, __float_as_int(x), 0x122, 0xf, 0xf, true); x += __int_as_float(_t); } \
  { int _t = __builtin_amdgcn_update_dpp(0, __float_as_int(x), 0x124, 0xf, 0xf, true); x += __int_as_float(_t); } \
  { int _t = __builtin_amdgcn_update_dpp(0, __float_as_int(x), 0x128, 0xf, 0xf, true); x += __int_as_float(_t); } }

// ---------------- kernel 0: weight prep (transpose -> bf16) ----------------
__global__ __launch_bounds__(256) void prep_kernel(
    const float* __restrict__ Wq, const float* __restrict__ Wk, const float* __restrict__ Wv,
    const float* __restrict__ Wo, const float* __restrict__ bq, const float* __restrict__ bk,
    const float* __restrict__ bv,
    unsigned short* __restrict__ Wt, unsigned short* __restrict__ Wot, float* __restrict__ bqkv)
{
  int idx = blockIdx.x * 256 + threadIdx.x;
  if (idx < 192 * 1024) {
    int n = idx >> 10, k = idx & 1023;
    const float* W = (n < 64) ? Wq : (n < 128) ? Wk : Wv;
    Wt[idx] = f2bf(W[k * 64 + (n & 63)]);
  } else if (idx < 192 * 1024 + 1024 * 64) {
    int j = idx - 192 * 1024;
    int n = j >> 6, k = j & 63;
    Wot[j] = f2bf(Wo[k * 1024 + n]);
  } else if (idx < 192 * 1024 + 1024 * 64 + 192) {
    int n = idx - (192 * 1024 + 1024 * 64);
    bqkv[n] = (n < 64) ? bq[n] : (n < 128) ? bk[n - 64] : bv[n - 128];
  }
}

// ---------------- fused kernel: QKV proj + banded attention + out proj ----------------
// Block = 64 q-rows, grid 256 (1 block/CU), 1024 threads = 16 waves (4/SIMD).
// R11 structure (52.8 us verified); R12 delta: ALL hot fp32->bf16 conversions
// go through v_cvt_pk_bf16_f32 (HW RNE pack) instead of manual bit-twiddle —
// ~6-10x fewer conversion VALU ops (VALUBusy was 23.5% and phase 1 is
// VALU/staging-bound, not MFMA-bound: R11 cut MFMA work 22%, time only -3%).
// NOTE (R9 lesson): compiler pins this kernel at the 64-VGPR occupancy step
// and SPILLS if pressure exceeds it — no distance-2 prefetch, no wb hoist.
// LDS map (bytes):
//   phase 1: A dbuf [0, 55296), B dbuf [55296, 110592)   (192 x 72 shorts each)
//   phase 2: Kl [0, 27648) (QK^T; then reused for Obf), Vt [27648, 55296),
//            PsU [55296, 76800)  time-muxed: Q(64x72) -> P(4x16x168)
//   always : Mx [110592), Lx [111616), biasL [112640)   (outside phase-1 region)
__global__ __launch_bounds__(1024, 4) void fused_attn(
    const float* __restrict__ X, const unsigned short* __restrict__ Wt,
    const float* __restrict__ bqkv, const float* __restrict__ bias,
    const unsigned short* __restrict__ Wot, const float* __restrict__ bo,
    float* __restrict__ out)
{
  __shared__ __align__(16) char smem[113664];
  unsigned short* const Kl  = (unsigned short*)(smem);            // [192][72]; later Obf [64][72]
  unsigned short* const Vt  = (unsigned short*)(smem + 27648);    // [64][216]
  unsigned short* const PsU = (unsigned short*)(smem + 55296);    // Q then P
  float* const Mx    = (float*)(smem + 110592);                   // [16][16]
  float* const Lx    = (float*)(smem + 111616);                   // [16][16]
  float* const biasL = (float*)(smem + 112640);                   // [129]
  unsigned short* const As_ = (unsigned short*)(smem);            // [2][192*72]
  unsigned short* const Bs_ = (unsigned short*)(smem + 55296);    // [2][192*72]

  int t = threadIdx.x;
  int lane = t & 63, w = t >> 6;
  int col = lane & 15, quad = lane >> 4, q4 = quad * 4;
  // XCD swizzle: each XCD gets one batch's 32 contiguous q-tiles (halo L2 reuse).
  int L = ((blockIdx.x & 7) << 5) | (blockIdx.x >> 3);
  int b = L >> 5;                    // batch
  int i0 = (L & 31) * 64;            // first q row (batch coords)
  const float* xbase = X + (size_t)(b << 11) * 1024;

  if (t < 129) biasL[t] = bias[1984 + t];   // region untouched by phase 1

  // ---- phase 1: window GEMM, BK=64, double-buffered, distance-1 prefetch ----
  // KV: wave (wm=w>>2, wn=w&3) owns 48 rows x 32 of the 128 K|V cols.
  // Q : wave (wm4=w&3, wn4=w>>2) owns 16 middle rows x 16 of the 64 Q cols.
  int wm = w >> 2, wn = w & 3;
  int wm4 = w & 3, wn4 = w >> 2;
  f32x4 acc[3][2] = {};
  f32x4 accq = {};
  int tr = t >> 4, c4 = t & 15;      // staging: 64 rows/slab, 16 chunks of 4
  int offA[3], offB[3];
  #pragma unroll
  for (int i = 0; i < 3; ++i) {
    int row = i * 64 + tr;           // window row 0..191
    int jb = i0 - 64 + row;
    int jc = jb < 0 ? 0 : (jb > 2047 ? 2047 : jb);
    offA[i] = jc * 1024 + c4 * 4;
    offB[i] = row * 1024 + c4 * 4;
  }
  float bov[2], bovq;
  #pragma unroll
  for (int nt = 0; nt < 2; ++nt) bov[nt] = bqkv[64 + wn * 32 + nt * 16 + col];
  bovq = bqkv[wn4 * 16 + col];

  float4 pA[3]; uint2 pB[3];
  #pragma unroll
  for (int i = 0; i < 3; ++i) {
    pA[i] = *(const float4*)(xbase + offA[i]);
    pB[i] = *(const uint2*)(Wt + offB[i]);
  }
  for (int ks = 0; ks < 16; ++ks) {
    unsigned short* A  = As_ + (ks & 1) * 13824;
    unsigned short* Bb = Bs_ + (ks & 1) * 13824;
    #pragma unroll
    for (int i = 0; i < 3; ++i) {    // staged regs -> LDS[cur]; HW cvt_pk
      *(uint2*)(A  + (i * 64 + tr) * 72 + c4 * 4) =
          make_uint2(cvtpk(pA[i].x, pA[i].y), cvtpk(pA[i].z, pA[i].w));
      *(uint2*)(Bb + (i * 64 + tr) * 72 + c4 * 4) = pB[i];
    }
    if (ks + 1 < 16) {               // next tile's loads issued before barrier
      #pragma unroll
      for (int i = 0; i < 3; ++i) {
        pA[i] = *(const float4*)(xbase + offA[i] + (ks + 1) * 64);
        pB[i] = *(const uint2*)(Wt + offB[i] + (ks + 1) * 64);
      }
    }
    BAR_LGKM();
    // race-free: a wave's buf-X ds_reads drain (own lgkmcnt 0) before it
    // signals the next barrier; buf-X is rewritten 2 iters later, after it.
    __builtin_amdgcn_s_setprio(1);
    #pragma unroll
    for (int kk = 0; kk < 64; kk += 32) {
      int ko = kk + quad * 8;
      // KV-GEMM: B rows 64 + wn*32 + nt*16 (K and V weight cols)
      bf16x8 bfr[2];
      #pragma unroll
      for (int nt = 0; nt < 2; ++nt)
        bfr[nt] = *(const bf16x8*)(Bb + ((64 + wn * 32 + nt * 16) + col) * 72 + ko);
      #pragma unroll
      for (int mt = 0; mt < 3; ++mt) {
        bf16x8 afr = *(const bf16x8*)(A + ((wm * 48 + mt * 16) + col) * 72 + ko);
        #pragma unroll
        for (int nt = 0; nt < 2; ++nt)
          acc[mt][nt] = __builtin_amdgcn_mfma_f32_16x16x32_bf16(afr, bfr[nt], acc[mt][nt], 0, 0, 0);
      }
      // Q-GEMM: middle 64 A rows only, B rows 0..63 (Q weight cols)
      {
        bf16x8 aq_ = *(const bf16x8*)(A + ((64 + wm4 * 16) + col) * 72 + ko);
        bf16x8 bq_ = *(const bf16x8*)(Bb + ((wn4 * 16) + col) * 72 + ko);
        accq = __builtin_amdgcn_mfma_f32_16x16x32_bf16(aq_, bq_, accq, 0, 0, 0);
      }
    }
    __builtin_amdgcn_s_setprio(0);
  }
  BAR_LGKM();        // last-buf ds_reads done before LDS repurpose

  // ---- phase 1b: accumulators (+bias, ->bf16) into phase-2 layouts ----
  // Waves wn in {0,1} hold pure K cols; wn in {2,3} pure V cols. All waves hold Q.
  #pragma unroll
  for (int mt = 0; mt < 3; ++mt) {
    int mbase = wm * 48 + mt * 16 + q4;
    #pragma unroll
    for (int nt = 0; nt < 2; ++nt) {
      int n = wn * 32 + nt * 16 + col;         // 0..127 over K|V
      unsigned int u01 = cvtpk(acc[mt][nt][0] + bov[nt], acc[mt][nt][1] + bov[nt]);
      unsigned int u23 = cvtpk(acc[mt][nt][2] + bov[nt], acc[mt][nt][3] + bov[nt]);
      if (wn < 2) {                            // K: stride-72 scatter
        Kl[(mbase + 0) * 72 + n] = (unsigned short)u01;
        Kl[(mbase + 1) * 72 + n] = (unsigned short)(u01 >> 16);
        Kl[(mbase + 2) * 72 + n] = (unsigned short)u23;
        Kl[(mbase + 3) * 72 + n] = (unsigned short)(u23 >> 16);
      } else {                                 // V^T: m contiguous -> one uint2
        *(uint2*)(Vt + (n - 64) * 216 + mbase) = make_uint2(u01, u23);
      }
    }
  }
  { // Q tile: rows 0..63 (window rows 64..127), cols 0..63
    unsigned int u01 = cvtpk(accq[0] + bovq, accq[1] + bovq);
    unsigned int u23 = cvtpk(accq[2] + bovq, accq[3] + bovq);
    int qoff = wn4 * 16 + col;
    PsU[(wm4 * 16 + q4 + 0) * 72 + qoff] = (unsigned short)u01;
    PsU[(wm4 * 16 + q4 + 1) * 72 + qoff] = (unsigned short)(u01 >> 16);
    PsU[(wm4 * 16 + q4 + 2) * 72 + qoff] = (unsigned short)u23;
    PsU[(wm4 * 16 + q4 + 3) * 72 + qoff] = (unsigned short)(u23 >> 16);
  }
  if (t < 256) { // zero-fill Vt j-cols 192..207 (PV k-chunk overhang)
    int pz = t >> 2, c0 = 192 + (t & 3) * 4;
    *(uint2*)(Vt + pz * 216 + c0) = make_uint2(0u, 0u);
  }
  BAR_LGKM();

  // ---- phase 2: banded attention; g = q-subtile (16 rows), u = worker ----
  int g = w >> 2, u = w & 3;
  int iq = i0 + g * 16;
  bf16x8 aq0 = *(const bf16x8*)(PsU + (g * 16 + col) * 72 + quad * 8);
  bf16x8 aq1 = *(const bf16x8*)(PsU + (g * 16 + col) * 72 + 32 + quad * 8);

  // QK^T: j-tiles split u=0:{0,1,2} u=1:{3,4} u=2:{5,6} u=3:{7,8}
  int nt9 = (u == 0) ? 3 : 2;
  int t9b = (u == 0) ? 0 : (2 * u + 1);
  f32x4 sv[3];
  for (int i = 0; i < nt9; ++i) {
    int t9 = t9b + i;
    int krow = ((g + t9) * 16 + col) * 72;
    bf16x8 kb0 = *(const bf16x8*)(Kl + krow + quad * 8);
    bf16x8 kb1 = *(const bf16x8*)(Kl + krow + 32 + quad * 8);
    f32x4 z = {};
    z = __builtin_amdgcn_mfma_f32_16x16x32_bf16(aq0, kb0, z, 0, 0, 0);
    sv[i] = __builtin_amdgcn_mfma_f32_16x16x32_bf16(aq1, kb1, z, 0, 0, 0);
  }
  float mrow[4] = {-3e38f, -3e38f, -3e38f, -3e38f};
  for (int i = 0; i < nt9; ++i) {
    int t9 = t9b + i;
    int j = iq - 64 + t9 * 16 + col;
    #pragma unroll
    for (int r = 0; r < 4; ++r) {
      int diff = q4 + r + 64 - t9 * 16 - col;   // i - j
      bool valid = (j >= 0) & (j < 2048) & (diff >= -64) & (diff <= 64);
      int bi = 64 - diff; bi = bi < 0 ? 0 : (bi > 128 ? 128 : bi);
      float x = valid ? (sv[i][r] * 0.125f + biasL[bi]) : -3e38f;
      sv[i][r] = x;
      mrow[r] = fmaxf(mrow[r], x);
    }
  }
  #pragma unroll
  for (int r = 0; r < 4; ++r) ROW16_MAX(mrow[r]);
  if (col == 0) {
    #pragma unroll
    for (int r = 0; r < 4; ++r) Mx[w * 16 + q4 + r] = mrow[r];
  }
  BAR_LGKM();   // also guarantees all Kl (QK^T) reads drained block-wide
  #pragma unroll
  for (int r = 0; r < 4; ++r) {
    float m0_ = Mx[(g * 4 + 0) * 16 + q4 + r];
    float m1_ = Mx[(g * 4 + 1) * 16 + q4 + r];
    float m2_ = Mx[(g * 4 + 2) * 16 + q4 + r];
    float m3_ = Mx[(g * 4 + 3) * 16 + q4 + r];
    mrow[r] = fmaxf(fmaxf(m0_, m1_), fmaxf(m2_, m3_));
  }

  unsigned short* Pw = PsU + g * 2688;       // 16 rows x 168
  float lsum[4] = {0.f, 0.f, 0.f, 0.f};
  for (int i = 0; i < nt9; ++i) {
    int t9 = t9b + i;
    float pe[4];
    #pragma unroll
    for (int r = 0; r < 4; ++r) {
      pe[r] = __expf(sv[i][r] - mrow[r]);
      lsum[r] += pe[r];
    }
    unsigned int u01 = cvtpk(pe[0], pe[1]);
    unsigned int u23 = cvtpk(pe[2], pe[3]);
    int poff = t9 * 16 + col;
    Pw[(q4 + 0) * 168 + poff] = (unsigned short)u01;
    Pw[(q4 + 1) * 168 + poff] = (unsigned short)(u01 >> 16);
    Pw[(q4 + 2) * 168 + poff] = (unsigned short)u23;
    Pw[(q4 + 3) * 168 + poff] = (unsigned short)(u23 >> 16);
  }
  #pragma unroll
  for (int r = 0; r < 4; ++r) ROW16_SUM(lsum[r]);
  if (col == 0) {
    #pragma unroll
    for (int r = 0; r < 4; ++r) Lx[w * 16 + q4 + r] = lsum[r];
  }
  if (u == 0) {
    #pragma unroll
    for (int r = 0; r < 4; ++r) Pw[(q4 + r) * 168 + 144 + col] = 0;
  }
  BAR_LGKM();
  #pragma unroll
  for (int r = 0; r < 4; ++r)
    lsum[r] = Lx[(g * 4 + 0) * 16 + q4 + r] + Lx[(g * 4 + 1) * 16 + q4 + r]
            + Lx[(g * 4 + 2) * 16 + q4 + r] + Lx[(g * 4 + 3) * 16 + q4 + r];

  // PV: wave u owns p-block u (16 cols) over all 5 k-chunks
  f32x4 o = {};
  #pragma unroll
  for (int kc = 0; kc < 5; ++kc) {
    bf16x8 pa = *(const bf16x8*)(Pw + col * 168 + kc * 32 + quad * 8);
    bf16x8 vb = *(const bf16x8*)(Vt + (u * 16 + col) * 216 + g * 16 + kc * 32 + quad * 8);
    o = __builtin_amdgcn_mfma_f32_16x16x32_bf16(pa, vb, o, 0, 0, 0);
  }
  // Normalized O parked in the Kl region (dead since the Mx barrier) — no
  // barrier needed before these writes; P region stays untouched.
  {
    float rl[4];
    #pragma unroll
    for (int r = 0; r < 4; ++r) rl[r] = 1.0f / lsum[r];
    unsigned int u01 = cvtpk(o[0] * rl[0], o[1] * rl[1]);
    unsigned int u23 = cvtpk(o[2] * rl[2], o[3] * rl[3]);
    int ooff = u * 16 + col;
    Kl[(g * 16 + q4 + 0) * 72 + ooff] = (unsigned short)u01;
    Kl[(g * 16 + q4 + 1) * 72 + ooff] = (unsigned short)(u01 >> 16);
    Kl[(g * 16 + q4 + 2) * 72 + ooff] = (unsigned short)u23;
    Kl[(g * 16 + q4 + 3) * 72 + ooff] = (unsigned short)(u23 >> 16);
  }
  BAR_LGKM();

  // ---- phase 3: out[64 q][1024 n] = Obf @ Wot + bo; wave owns 64 n-cols ----
  int n0 = w * 64;
  const unsigned short* wb_base = Wot + (size_t)(n0 + col) * 64 + quad * 8;
  bf16x8 wb[4][2];
  #pragma unroll
  for (int ns = 0; ns < 4; ++ns) {
    wb[ns][0] = *(const bf16x8*)(wb_base + ns * 16 * 64);
    wb[ns][1] = *(const bf16x8*)(wb_base + ns * 16 * 64 + 32);
  }
  float bov4[4];
  #pragma unroll
  for (int ns = 0; ns < 4; ++ns) bov4[ns] = bo[n0 + ns * 16 + col];
  float* outbase = out + ((size_t)(b << 11) + i0) * 1024 + n0;
  #pragma unroll
  for (int mt = 0; mt < 4; ++mt) {
    bf16x8 a0 = *(const bf16x8*)(Kl + (mt * 16 + col) * 72 + quad * 8);
    bf16x8 a1 = *(const bf16x8*)(Kl + (mt * 16 + col) * 72 + 32 + quad * 8);
    f32x4 a4[4] = {};
    #pragma unroll
    for (int ns = 0; ns < 4; ++ns) {
      a4[ns] = __builtin_amdgcn_mfma_f32_16x16x32_bf16(a0, wb[ns][0], a4[ns], 0, 0, 0);
      a4[ns] = __builtin_amdgcn_mfma_f32_16x16x32_bf16(a1, wb[ns][1], a4[ns], 0, 0, 0);
    }
    #pragma unroll
    for (int ns = 0; ns < 4; ++ns)
      #pragma unroll
      for (int r = 0; r < 4; ++r)
        outbase[(size_t)(mt * 16 + q4 + r) * 1024 + ns * 16 + col] = a4[ns][r] + bov4[ns];
  }
}

// ---------------- launch ----------------
extern "C" void kernel_launch(void* const* d_in, const int* in_sizes, int n_in,
                              void* d_out, int out_size, void* d_ws, size_t ws_size,
                              hipStream_t stream) {
  const float* X    = (const float*)d_in[0];
  // d_in[1] = attention_mask: per-row constant shift -> softmax-invariant, unused
  const float* Wq   = (const float*)d_in[2];
  const float* bq   = (const float*)d_in[3];
  const float* Wk   = (const float*)d_in[4];
  const float* bk   = (const float*)d_in[5];
  const float* Wv   = (const float*)d_in[6];
  const float* bv   = (const float*)d_in[7];
  const float* Wo   = (const float*)d_in[8];
  const float* bo   = (const float*)d_in[9];
  const float* bias = (const float*)d_in[10];
  float* out = (float*)d_out;
  char* ws = (char*)d_ws;
  unsigned short* Wt   = (unsigned short*)(ws);              //   393,216 B
  unsigned short* Wot  = (unsigned short*)(ws + 393216);     //   131,072 B
  float*          bqkv = (float*)(ws + 524288);              //       768 B

  prep_kernel<<<1025, 256, 0, stream>>>(Wq, Wk, Wv, Wo, bq, bk, bv, Wt, Wot, bqkv);
  fused_attn<<<256, 1024, 0, stream>>>(X, Wt, bqkv, bias, Wot, bo, out);
}